// Round 7
// baseline (228.661 us; speedup 1.0000x reference)
//
#include <hip/hip_runtime.h>

// ---------------------------------------------------------------------------
// ConvFeatureExtractor: profile = rownorm( freq @ softmax(matches/T, axis=1)^T )
//   matches[f,i] = Thi[f,i>>6] + Tlo[f,i&63] (separable) => probs = e1 x e2.
// R7: gemm is at the m97 structural plateau (855 TF = 41% dense; occupancy and
//     staging levers proven dead in R4/R6). Attack the ~82 us non-gemm side:
//       - prep_kernel = cast + tables fused (coalesced E1t via LDS transpose)
//         + per-block S partials (Svec[i] = sum_f bf16(e1'e2), bf16-rounded to
//         match the gemm numerator quantization exactly)
//       - denom_kernel: Svec reduce + invDenom[b] = 1/(freqb . Svec)
//       - gemm epilogue scales by invDenom -> norm_kernel deleted, out written
//         once. 4 dispatches -> 3.
// ---------------------------------------------------------------------------

typedef __bf16  bf16x8 __attribute__((ext_vector_type(8)));
typedef float   f32x4  __attribute__((ext_vector_type(4)));

#define GLD16(gp, lp)                                                          \
  __builtin_amdgcn_global_load_lds(                                            \
      (const __attribute__((address_space(1))) void*)(gp),                     \
      (__attribute__((address_space(3))) void*)(lp), 16, 0, 0)

__device__ __forceinline__ short f2bf(float x) {
  unsigned u = __float_as_uint(x);
  unsigned r = (u + 0x7fffu + ((u >> 16) & 1u)) >> 16;   // RNE
  return (short)r;
}
__device__ __forceinline__ float bf_round(float x) {     // f32 -> bf16 -> f32 (RNE)
  unsigned u = __float_as_uint(x);
  unsigned r = (u + 0x7fffu + ((u >> 16) & 1u)) & 0xffff0000u;
  return __uint_as_float(r);
}
__device__ __forceinline__ float bf2f(unsigned short u) {
  return __uint_as_float(((unsigned)u) << 16);
}

__device__ __forceinline__ float wave_max(float v) {
  #pragma unroll
  for (int off = 32; off; off >>= 1) v = fmaxf(v, __shfl_xor(v, off, 64));
  return v;
}
__device__ __forceinline__ float wave_sum(float v) {
  #pragma unroll
  for (int off = 32; off; off >>= 1) v += __shfl_xor(v, off, 64);
  return v;
}

// ---------------- k1: prep = cast (blocks 0..4095) + tables (blocks 4096..4223)
// tables block bb handles 64 filters f0=bb*64:
//   E1loc[floc][h] = e1*invZ, E2loc[floc][l] = e2   (LDS)
//   S_part[bb][h*64+l] = sum_{floc} bf16(E1loc*E2loc)  (matches gemm B quant)
//   E1t[h][f] (coalesced via transpose), E2[f][l] (coalesced)
__global__ __launch_bounds__(256) void prep_kernel(const float* __restrict__ freq,
                                                   const float* __restrict__ kp,
                                                   const float* __restrict__ temp,
                                                   short* __restrict__ freqb,
                                                   float* __restrict__ E1t,
                                                   float* __restrict__ E2,
                                                   float* __restrict__ S_part) {
  __shared__ float E1loc[64][64];
  __shared__ float E2loc[64][64];
  const int blk = blockIdx.x;
  const int t = threadIdx.x;

  if (blk < 4096) {                     // ---- cast part: freq f32 -> bf16
    int idx = blk * 256 + t;
    float4 v = ((const float4*)freq)[idx];
    short4 o;
    o.x = f2bf(v.x); o.y = f2bf(v.y); o.z = f2bf(v.z); o.w = f2bf(v.w);
    ((short4*)freqb)[idx] = o;
    return;
  }

  // ---- tables part
  const int bb = blk - 4096;            // 0..127
  const int f0 = bb * 64;
  const int lane = t & 63, wave = t >> 6;
  const float invT = 1.0f / temp[0];
  const int d0 = (lane >> 4) & 3, d1 = (lane >> 2) & 3, d2 = lane & 3;

  #pragma unroll
  for (int ffi = 0; ffi < 16; ffi++) {
    const int floc = wave * 16 + ffi;
    const float* P = kp + (size_t)(f0 + floc) * 24;
    const float thi = P[d0 * 6 + 0] + P[d1 * 6 + 1] + P[d2 * 6 + 2];
    const float tlo = P[d0 * 6 + 3] + P[d1 * 6 + 4] + P[d2 * 6 + 5];
    const float mxhi = wave_max(thi), mxlo = wave_max(tlo);
    const float e1 = __expf((thi - mxhi) * invT);
    const float e2 = __expf((tlo - mxlo) * invT);
    const float s1 = wave_sum(e1), s2 = wave_sum(e2);
    const float invZ = 1.0f / (s1 * s2);
    E1loc[floc][lane] = e1 * invZ;
    E2loc[floc][lane] = e2;
  }
  __syncthreads();

  // S partial: thread owns h = t>>2, l in [ (t&3)*16, +16 )
  {
    const int h = t >> 2, lb = (t & 3) * 16;
    float acc[16];
    #pragma unroll
    for (int ll = 0; ll < 16; ll++) acc[ll] = 0.0f;
    for (int ff = 0; ff < 64; ff++) {
      const float a = E1loc[ff][h];
      #pragma unroll
      for (int ll = 0; ll < 16; ll++)
        acc[ll] += bf_round(a * E2loc[ff][lb + ll]);
    }
    float* dst = S_part + (size_t)bb * 4096 + h * 64 + lb;
    #pragma unroll
    for (int q = 0; q < 4; q++)
      ((f32x4*)dst)[q] = (f32x4){acc[q*4], acc[q*4+1], acc[q*4+2], acc[q*4+3]};
  }

  // E1t[h][f] coalesced write: thread: h = t>>2, f-range (t&3)*16
  {
    const int h = t >> 2, c0 = (t & 3) * 16;
    float tmp[16];
    #pragma unroll
    for (int cc = 0; cc < 16; cc++) tmp[cc] = E1loc[c0 + cc][h];
    float* dst = E1t + (size_t)h * 8192 + f0 + c0;
    #pragma unroll
    for (int q = 0; q < 4; q++)
      ((f32x4*)dst)[q] = (f32x4){tmp[q*4], tmp[q*4+1], tmp[q*4+2], tmp[q*4+3]};
  }

  // E2[f][l] coalesced write: thread: floc = t>>2, l-range (t&3)*16
  {
    const int fl = t >> 2, l0 = (t & 3) * 16;
    float* dst = E2 + (size_t)(f0 + fl) * 64 + l0;
    #pragma unroll
    for (int q = 0; q < 4; q++)
      ((f32x4*)dst)[q] = *(const f32x4*)&E2loc[fl][l0 + q * 4];
  }
}

// ---------------- k2: denom — Svec = sum_p S_part[p]; invDenom[b] = 1/(freqb.Svec)
// grid 64 blocks x 16 rows.
__global__ __launch_bounds__(256) void denom_kernel(const short* __restrict__ freqb,
                                                    const float* __restrict__ S_part,
                                                    float* __restrict__ invDenom) {
  __shared__ float Svec[4096];
  const int t = threadIdx.x;
  const int b0 = blockIdx.x * 16;

  {                                     // reduce S_part over the 128 partials
    const int i0 = t * 16;
    float acc[16];
    #pragma unroll
    for (int q = 0; q < 16; q++) acc[q] = 0.0f;
    for (int p = 0; p < 128; p++) {
      const f32x4* src = (const f32x4*)(S_part + (size_t)p * 4096 + i0);
      #pragma unroll
      for (int q = 0; q < 4; q++) {
        f32x4 v = src[q];
        acc[q*4+0] += v.x; acc[q*4+1] += v.y; acc[q*4+2] += v.z; acc[q*4+3] += v.w;
      }
    }
    #pragma unroll
    for (int q = 0; q < 4; q++)
      ((f32x4*)(Svec + i0))[q] = (f32x4){acc[q*4], acc[q*4+1], acc[q*4+2], acc[q*4+3]};
  }
  __syncthreads();

  const int lane = t & 63, wave = t >> 6;
  #pragma unroll
  for (int rr = 0; rr < 4; rr++) {
    const int row = b0 + wave * 4 + rr;
    const unsigned short* fr = (const unsigned short*)(freqb + (size_t)row * 4096);
    float s = 0.0f;
    #pragma unroll
    for (int ch = 0; ch < 16; ch++) {
      const int i = ch * 256 + lane * 4;
      ushort4 u = *(const ushort4*)(fr + i);
      f32x4 sv = *(const f32x4*)(Svec + i);
      s += bf2f(u.x) * sv.x + bf2f(u.y) * sv.y + bf2f(u.z) * sv.z + bf2f(u.w) * sv.w;
    }
    const float tot = wave_sum(s);
    if (lane == 0) invDenom[row] = 1.0f / tot;
  }
}

// ---------------- k3: GEMM pooled = A(1024x4096) * B^T, B[f,i]=e1[f,i>>6]e2[f,i&63]
// Tiles: TM=64, TN=128, BK=64; grid 64x16 = 1024 blocks. Epilogue scales by
// invDenom (row-normalization fused). Only A staged in LDS (XOR-swizzled:
// row stride 128B == 32 banks otherwise). B built in regs from e1/e2.
__global__ __launch_bounds__(256, 4) void gemm_kernel(const short* __restrict__ A,
                                                      const float* __restrict__ E1t,
                                                      const float* __restrict__ E2,
                                                      const float* __restrict__ invDenom,
                                                      float* __restrict__ C) {
  __shared__ short As[64 * 64];

  const int t = threadIdx.x;
  const int lane = t & 63, wave = t >> 6;
  const int quad = lane >> 4, l16 = lane & 15;
  const int m0 = blockIdx.y * 64;        // batch tile
  const int n0 = blockIdx.x * 128;       // filter tile
  const int wn = wave * 32;              // wave's n-offset within tile

  f32x4 acc[4][2];
  #pragma unroll
  for (int i = 0; i < 4; i++)
    #pragma unroll
    for (int j = 0; j < 2; j++) acc[i][j] = (f32x4){0.f, 0.f, 0.f, 0.f};

  int nrow[2];
  #pragma unroll
  for (int j = 0; j < 2; j++) nrow[j] = n0 + wn + j * 16 + l16;
  float4 e2a[2][2], e2b[2][2];
  #pragma unroll
  for (int j = 0; j < 2; j++)
    #pragma unroll
    for (int ks = 0; ks < 2; ks++) {
      const float* p = E2 + (size_t)nrow[j] * 64 + (ks * 4 + quad) * 8;
      e2a[j][ks] = *(const float4*)p;
      e2b[j][ks] = *(const float4*)(p + 4);
    }

  const int lane_row = lane >> 3;                      // 0..7 within chunk
  const int src_col = ((lane & 7) ^ lane_row) * 8;     // swizzled global col (shorts)
  const int sw = l16 & 7;                              // reader swizzle key (= row&7)

  for (int kt = 0; kt < 64; kt++) {
    const int kofs = kt * 64;
    float e1v[2];
    #pragma unroll
    for (int j = 0; j < 2; j++) e1v[j] = E1t[kt * 8192 + nrow[j]];

    __syncthreads();
    #pragma unroll
    for (int c = 0; c < 2; c++) {
      const int chunk = wave * 2 + c;                  // 0..7
      const int row = chunk * 8 + lane_row;            // 0..63
      GLD16(A + (m0 + row) * 4096 + kofs + src_col, &As[chunk * 512 + lane * 8]);
    }
    __syncthreads();

    bf16x8 b[2][2];
    #pragma unroll
    for (int j = 0; j < 2; j++)
      #pragma unroll
      for (int ks = 0; ks < 2; ks++) {
        const float s = e1v[j];
        bf16x8 bb;
        bb[0] = (__bf16)(s * e2a[j][ks].x);
        bb[1] = (__bf16)(s * e2a[j][ks].y);
        bb[2] = (__bf16)(s * e2a[j][ks].z);
        bb[3] = (__bf16)(s * e2a[j][ks].w);
        bb[4] = (__bf16)(s * e2b[j][ks].x);
        bb[5] = (__bf16)(s * e2b[j][ks].y);
        bb[6] = (__bf16)(s * e2b[j][ks].z);
        bb[7] = (__bf16)(s * e2b[j][ks].w);
        b[ks][j] = bb;
      }

    #pragma unroll
    for (int ks = 0; ks < 2; ks++) {
      const int pcol = ((ks * 4 + quad) ^ sw) * 8;     // physical col (shorts)
      bf16x8 a[4];
      #pragma unroll
      for (int i = 0; i < 4; i++)
        a[i] = *(const bf16x8*)&As[(i * 16 + l16) * 64 + pcol];
      #pragma unroll
      for (int i = 0; i < 4; i++)
        #pragma unroll
        for (int j = 0; j < 2; j++)
          acc[i][j] = __builtin_amdgcn_mfma_f32_16x16x32_bf16(a[i], b[ks][j], acc[i][j], 0, 0, 0);
    }
  }

  // epilogue: C/D layout col=lane&15, row=quad*4+reg; fused row-normalize
  float invd[4][4];
  #pragma unroll
  for (int i = 0; i < 4; i++)
    #pragma unroll
    for (int r = 0; r < 4; r++)
      invd[i][r] = invDenom[m0 + i * 16 + quad * 4 + r];

  #pragma unroll
  for (int i = 0; i < 4; i++) {
    #pragma unroll
    for (int r = 0; r < 4; r++) {
      const int brow = m0 + i * 16 + quad * 4 + r;
      float* crow = C + (size_t)brow * 8192 + n0 + wn + l16;
      #pragma unroll
      for (int j = 0; j < 2; j++) crow[j * 16] = acc[i][j][r] * invd[i][r];
    }
  }
}

// ---------------------------------------------------------------------------
extern "C" void kernel_launch(void* const* d_in, const int* in_sizes, int n_in,
                              void* d_out, int out_size, void* d_ws, size_t ws_size,
                              hipStream_t stream) {
  const float* freq    = (const float*)d_in[0];   // 1024*4096
  const float* kparams = (const float*)d_in[1];   // 8192*4*6
  const float* temp    = (const float*)d_in[2];   // 1
  // d_in[3] = kmer_idcs (recomputed analytically in-kernel)

  float* out = (float*)d_out;                     // 1024*8192 f32

  short* freqb = (short*)d_ws;                           // 8 MiB
  float* E1t   = (float*)(freqb + (size_t)1024 * 4096);  // 64*8192 f32 = 2 MiB
  float* E2    = E1t + (size_t)64 * 8192;                // 8192*64 f32 = 2 MiB
  float* S_part = E2 + (size_t)8192 * 64;                // 128*4096 f32 = 2 MiB
  float* invDenom = S_part + (size_t)128 * 4096;         // 1024 f32

  prep_kernel <<<4224, 256, 0, stream>>>(freq, kparams, temp, freqb, E1t, E2, S_part);
  denom_kernel<<<64, 256, 0, stream>>>(freqb, S_part, invDenom);
  gemm_kernel <<<dim3(64, 16), 256, 0, stream>>>(freqb, E1t, E2, invDenom, out);
}

// Round 8
// 181.215 us; speedup vs baseline: 1.2618x; 1.2618x over previous
//
#include <hip/hip_runtime.h>

// ---------------------------------------------------------------------------
// ConvFeatureExtractor: profile = rownorm( freq @ softmax(matches/T, axis=1)^T )
//   matches[f,i] = Thi[f,i>>6] + Tlo[f,i&63] (separable) => probs = e1 x e2.
// R8: revert R7's S_part/denom (the +66us regression; 128-block /64-block
//     latency-bound kernels). Keep cast+tables fusion (both proven cheap).
//     gemm: BK=256 (16 barrier-pairs instead of 64) to amortize the vmcnt
//     drain; LDS 32KB still allows 4 blocks/CU. norm_kernel (proven 11us) back.
// ---------------------------------------------------------------------------

typedef __bf16  bf16x8 __attribute__((ext_vector_type(8)));
typedef float   f32x4  __attribute__((ext_vector_type(4)));

#define GLD16(gp, lp)                                                          \
  __builtin_amdgcn_global_load_lds(                                            \
      (const __attribute__((address_space(1))) void*)(gp),                     \
      (__attribute__((address_space(3))) void*)(lp), 16, 0, 0)

__device__ __forceinline__ short f2bf(float x) {
  unsigned u = __float_as_uint(x);
  unsigned r = (u + 0x7fffu + ((u >> 16) & 1u)) >> 16;   // RNE
  return (short)r;
}

__device__ __forceinline__ float wave_max(float v) {
  #pragma unroll
  for (int off = 32; off; off >>= 1) v = fmaxf(v, __shfl_xor(v, off, 64));
  return v;
}
__device__ __forceinline__ float wave_sum(float v) {
  #pragma unroll
  for (int off = 32; off; off >>= 1) v += __shfl_xor(v, off, 64);
  return v;
}

// ---------------- k1: prep = cast (blocks 0..4095) + tables (blocks 4096..4223)
// tables block bb handles 64 filters f0=bb*64:
//   E1loc[floc][h] = e1*invZ, E2loc[floc][l] = e2  (LDS), then coalesced
//   E1t[h][f] (via transpose) and E2[f][l] writes.
__global__ __launch_bounds__(256) void prep_kernel(const float* __restrict__ freq,
                                                   const float* __restrict__ kp,
                                                   const float* __restrict__ temp,
                                                   short* __restrict__ freqb,
                                                   float* __restrict__ E1t,
                                                   float* __restrict__ E2) {
  __shared__ float E1loc[64][64];
  __shared__ float E2loc[64][64];
  const int blk = blockIdx.x;
  const int t = threadIdx.x;

  if (blk < 4096) {                     // ---- cast part: freq f32 -> bf16
    int idx = blk * 256 + t;
    float4 v = ((const float4*)freq)[idx];
    short4 o;
    o.x = f2bf(v.x); o.y = f2bf(v.y); o.z = f2bf(v.z); o.w = f2bf(v.w);
    ((short4*)freqb)[idx] = o;
    return;
  }

  // ---- tables part
  const int bb = blk - 4096;            // 0..127
  const int f0 = bb * 64;
  const int lane = t & 63, wave = t >> 6;
  const float invT = 1.0f / temp[0];
  const int d0 = (lane >> 4) & 3, d1 = (lane >> 2) & 3, d2 = lane & 3;

  #pragma unroll
  for (int ffi = 0; ffi < 16; ffi++) {
    const int floc = wave * 16 + ffi;
    const float* P = kp + (size_t)(f0 + floc) * 24;
    const float thi = P[d0 * 6 + 0] + P[d1 * 6 + 1] + P[d2 * 6 + 2];
    const float tlo = P[d0 * 6 + 3] + P[d1 * 6 + 4] + P[d2 * 6 + 5];
    const float mxhi = wave_max(thi), mxlo = wave_max(tlo);
    const float e1 = __expf((thi - mxhi) * invT);
    const float e2 = __expf((tlo - mxlo) * invT);
    const float s1 = wave_sum(e1), s2 = wave_sum(e2);
    const float invZ = 1.0f / (s1 * s2);
    E1loc[floc][lane] = e1 * invZ;
    E2loc[floc][lane] = e2;
  }
  __syncthreads();

  // E1t[h][f] coalesced write: thread: h = t>>2, f-range (t&3)*16
  {
    const int h = t >> 2, c0 = (t & 3) * 16;
    float tmp[16];
    #pragma unroll
    for (int cc = 0; cc < 16; cc++) tmp[cc] = E1loc[c0 + cc][h];
    float* dst = E1t + (size_t)h * 8192 + f0 + c0;
    #pragma unroll
    for (int q = 0; q < 4; q++)
      ((f32x4*)dst)[q] = (f32x4){tmp[q*4], tmp[q*4+1], tmp[q*4+2], tmp[q*4+3]};
  }

  // E2[f][l] coalesced write: thread: floc = t>>2, l-range (t&3)*16
  {
    const int fl = t >> 2, l0 = (t & 3) * 16;
    float* dst = E2 + (size_t)(f0 + fl) * 64 + l0;
    #pragma unroll
    for (int q = 0; q < 4; q++)
      ((f32x4*)dst)[q] = *(const f32x4*)&E2loc[fl][l0 + q * 4];
  }
}

// ---------------- k2: GEMM pooled = A(1024x4096) * B^T, B[f,i]=e1[f,i>>6]e2[f,i&63]
// Tiles: TM=64, TN=128, BK=256; grid 64x16 = 1024 blocks. 16 K-iterations,
// each staging 32KB of A (8 GLD16/wave) -> 4x fewer barrier drains than BK=64.
// LDS XOR-swizzled (low-3 col-block bits ^ row&7): row stride 512B == bank-
// aligned, fragment reads land 2 lanes/bank-group (free). B built in regs:
// i>>6 = kt*4+(ks>>1) selects e1; i&63 = (ks&1)*32+quad*8+jj selects e2.
__global__ __launch_bounds__(256, 3) void gemm_kernel(const short* __restrict__ A,
                                                      const float* __restrict__ E1t,
                                                      const float* __restrict__ E2,
                                                      float* __restrict__ C) {
  __shared__ short As[64 * 256];         // 32 KB

  const int t = threadIdx.x;
  const int lane = t & 63, wave = t >> 6;
  const int quad = lane >> 4, l16 = lane & 15;
  const int m0 = blockIdx.y * 64;        // batch tile
  const int n0 = blockIdx.x * 128;       // filter tile
  const int wn = wave * 32;              // wave's n-offset within tile

  f32x4 acc[4][2];
  #pragma unroll
  for (int i = 0; i < 4; i++)
    #pragma unroll
    for (int j = 0; j < 2; j++) acc[i][j] = (f32x4){0.f, 0.f, 0.f, 0.f};

  int nrow[2];
  #pragma unroll
  for (int j = 0; j < 2; j++) nrow[j] = n0 + wn + j * 16 + l16;

  // e2 fragments: par = ks&1 selects l-half; lane covers l = par*32+quad*8+0..7
  float4 e2a[2][2], e2b[2][2];
  #pragma unroll
  for (int j = 0; j < 2; j++)
    #pragma unroll
    for (int par = 0; par < 2; par++) {
      const float* p = E2 + (size_t)nrow[j] * 64 + par * 32 + quad * 8;
      e2a[j][par] = *(const float4*)p;
      e2b[j][par] = *(const float4*)(p + 4);
    }

  // staging geometry: chunk = wave*8+c (0..31) covers rows {chunk*2, chunk*2+1};
  // lane's LDS slot = chunk*1024B + lane*16B; row = chunk*2 + (lane>>5);
  // source col-block = (lane&31) ^ (row&7).
  const int lrow_half = lane >> 5;                     // 0..1
  const int pblk = lane & 31;                          // physical col-block
  const int sw = l16 & 7;                              // reader swizzle key

  for (int kt = 0; kt < 16; kt++) {
    const int kofs = kt * 256;

    float e1v[2][4];
    #pragma unroll
    for (int hh = 0; hh < 4; hh++)
      #pragma unroll
      for (int j = 0; j < 2; j++)
        e1v[j][hh] = E1t[(kt * 4 + hh) * 8192 + nrow[j]];

    __syncthreads();
    #pragma unroll
    for (int c = 0; c < 8; c++) {
      const int chunk = wave * 8 + c;                  // 0..31
      const int row = chunk * 2 + lrow_half;           // 0..63
      const int src_col = (pblk ^ (row & 7)) * 8;      // shorts
      GLD16(A + (m0 + row) * 4096 + kofs + src_col, &As[chunk * 512 + lane * 8]);
    }
    __syncthreads();

    #pragma unroll
    for (int ks = 0; ks < 8; ks++) {
      const int q = ks * 4 + quad;                     // col-block 0..31
      const int pcol = (q ^ sw) * 8;                   // physical col (shorts)
      bf16x8 a[4];
      #pragma unroll
      for (int i = 0; i < 4; i++)
        a[i] = *(const bf16x8*)&As[(i * 16 + l16) * 256 + pcol];

      const int hh = ks >> 1, par = ks & 1;
      bf16x8 b[2];
      #pragma unroll
      for (int j = 0; j < 2; j++) {
        const float s = e1v[j][hh];
        bf16x8 bb;
        bb[0] = (__bf16)(s * e2a[j][par].x);
        bb[1] = (__bf16)(s * e2a[j][par].y);
        bb[2] = (__bf16)(s * e2a[j][par].z);
        bb[3] = (__bf16)(s * e2a[j][par].w);
        bb[4] = (__bf16)(s * e2b[j][par].x);
        bb[5] = (__bf16)(s * e2b[j][par].y);
        bb[6] = (__bf16)(s * e2b[j][par].z);
        bb[7] = (__bf16)(s * e2b[j][par].w);
        b[j] = bb;
      }

      #pragma unroll
      for (int i = 0; i < 4; i++)
        #pragma unroll
        for (int j = 0; j < 2; j++)
          acc[i][j] = __builtin_amdgcn_mfma_f32_16x16x32_bf16(a[i], b[j], acc[i][j], 0, 0, 0);
    }
  }

  // epilogue: C/D layout col=lane&15, row=quad*4+reg
  #pragma unroll
  for (int i = 0; i < 4; i++) {
    #pragma unroll
    for (int r = 0; r < 4; r++) {
      const int brow = m0 + i * 16 + quad * 4 + r;
      float* crow = C + (size_t)brow * 8192 + n0 + wn + l16;
      #pragma unroll
      for (int j = 0; j < 2; j++) crow[j * 16] = acc[i][j][r];
    }
  }
}

// ---------------- k3: row-normalize d_out (1024 rows of 8192) ----------------
__global__ __launch_bounds__(256) void norm_kernel(float* __restrict__ out) {
  const int b = blockIdx.x;
  const int t = threadIdx.x;
  const int lane = t & 63, wave = t >> 6;
  __shared__ float red[4];

  float4* row = (float4*)(out + (size_t)b * 8192);   // 2048 float4
  float4 v[8];
  float s = 0.0f;
  #pragma unroll
  for (int q = 0; q < 8; q++) {
    v[q] = row[q * 256 + t];
    s += (v[q].x + v[q].y) + (v[q].z + v[q].w);
  }
  float ws = wave_sum(s);
  if (lane == 0) red[wave] = ws;
  __syncthreads();
  float tot = (red[0] + red[1]) + (red[2] + red[3]);
  float inv = 1.0f / tot;
  #pragma unroll
  for (int q = 0; q < 8; q++) {
    v[q].x *= inv; v[q].y *= inv; v[q].z *= inv; v[q].w *= inv;
    row[q * 256 + t] = v[q];
  }
}

// ---------------------------------------------------------------------------
extern "C" void kernel_launch(void* const* d_in, const int* in_sizes, int n_in,
                              void* d_out, int out_size, void* d_ws, size_t ws_size,
                              hipStream_t stream) {
  const float* freq    = (const float*)d_in[0];   // 1024*4096
  const float* kparams = (const float*)d_in[1];   // 8192*4*6
  const float* temp    = (const float*)d_in[2];   // 1
  // d_in[3] = kmer_idcs (recomputed analytically in-kernel)

  float* out = (float*)d_out;                     // 1024*8192 f32

  short* freqb = (short*)d_ws;                           // 8 MiB
  float* E1t   = (float*)(freqb + (size_t)1024 * 4096);  // 64*8192 f32 = 2 MiB
  float* E2    = E1t + (size_t)64 * 8192;                // 8192*64 f32 = 2 MiB

  prep_kernel<<<4224, 256, 0, stream>>>(freq, kparams, temp, freqb, E1t, E2);
  gemm_kernel<<<dim3(64, 16), 256, 0, stream>>>(freqb, E1t, E2, out);
  norm_kernel<<<1024, 256, 0, stream>>>(out);
}